// Round 6
// baseline (26.086 us; speedup 1.0000x reference)
//
#include <hip/hip_runtime.h>

// KAN edge function:
//   out = w_base * silu(x) + w_spline * sum_b basis_b(x) * c_b
// Uniform cubic B-spline, GRID_SIZE=8, DEGREE=3 -> 11 bases; knots
// knots[k] = -8.75 + 1.25*k (15 knots, 14 deg-0 intervals). For x in
// interval j with t = (x-knot_j)/h, spline collapses to a per-interval
// cubic a + b t + c t^2 + d t^3 (coeffs built once per block into LDS).
//
// History: R1 26.39us grid-stride. R2 nt REGRESSED (28.9). R4 rcp+clamp
// NEUTRAL (26.38) -> compute off critical path. R5 exact-cover 2xfloat4
// WIN (24.8) -> per-thread MLP was limiting. R6: 4xfloat4 per thread,
// 64 B/lane in flight, single pass, exact cover (n4 = 4 * 2^20).

constexpr int NUM_BASIS = 11;
constexpr int NUM_INTERVALS = 14;

typedef float fx4 __attribute__((ext_vector_type(4)));

__device__ __forceinline__ float kan_elem(float xv, float wb, float ws,
                                          const float4* __restrict__ poly) {
    // silu: x * sigmoid(x); v_rcp_f32 (~1 ulp) instead of IEEE divide
    float sig = __builtin_amdgcn_rcpf(1.f + __expf(-xv));
    float base = xv * sig;
    // spline: interval index + local param
    float u = (xv + 8.75f) * 0.8f;   // (x - knot0) / h
    float jf = floorf(u);
    float t = u - jf;
    int j = (int)jf;
    // branchless clamp: input is N(0,1) (|x| < ~5.7 << 8.75) -> clamp
    // never changes a reachable value.
    j = min(max(j, 0), NUM_INTERVALS - 1);
    float4 p = poly[j];
    float sp = fmaf(fmaf(fmaf(p.w, t, p.z), t, p.y), t, p.x);
    return fmaf(wb, base, ws * sp);
}

__global__ __launch_bounds__(256) void kan_edge_kernel(
    const float* __restrict__ x,
    const float* __restrict__ w_base_p,
    const float* __restrict__ w_spline_p,
    const float* __restrict__ coeffs,
    float* __restrict__ out,
    int n4, int total)
{
    __shared__ float4 poly[NUM_INTERVALS];

    int tid = threadIdx.x;
    if (tid < NUM_INTERVALS) {
        int j = tid;
        float c0 = (j - 3 >= 0 && j - 3 < NUM_BASIS) ? coeffs[j - 3] : 0.f;
        float c1 = (j - 2 >= 0 && j - 2 < NUM_BASIS) ? coeffs[j - 2] : 0.f;
        float c2 = (j - 1 >= 0 && j - 1 < NUM_BASIS) ? coeffs[j - 1] : 0.f;
        float c3 = (j     < NUM_BASIS)               ? coeffs[j]     : 0.f;
        float a  = (c0 + 4.f * c1 + c2) * (1.f / 6.f);
        float b  = (c2 - c0) * 0.5f;
        float cc = (c0 - 2.f * c1 + c2) * 0.5f;
        float dd = (3.f * (c1 - c2) + (c3 - c0)) * (1.f / 6.f);
        poly[j] = make_float4(a, b, cc, dd);
    }
    __syncthreads();

    const float wb = w_base_p[0];
    const float ws = w_spline_p[0];

    const fx4* __restrict__ x4 = (const fx4*)x;
    fx4* __restrict__ o4 = (fx4*)out;

    // exact cover: each thread handles float4s i, i+s, i+2s, i+3s.
    // stride = total threads, so every load instruction in a wave covers
    // a contiguous 1 KB segment; 4 loads (64 B/lane) issue before the
    // dependent compute -> store chain.
    int i = blockIdx.x * blockDim.x + threadIdx.x;
    int stride = gridDim.x * blockDim.x;

    int i0 = i;
    int i1 = i + stride;
    int i2 = i + 2 * stride;
    int i3 = i + 3 * stride;

    if (i3 < n4) {
        // fast path: all four in range (true for the 8192x2048 shape)
        fx4 v0 = x4[i0];
        fx4 v1 = x4[i1];
        fx4 v2 = x4[i2];
        fx4 v3 = x4[i3];
        fx4 r0, r1, r2, r3;
#pragma unroll
        for (int k = 0; k < 4; ++k) r0[k] = kan_elem(v0[k], wb, ws, poly);
#pragma unroll
        for (int k = 0; k < 4; ++k) r1[k] = kan_elem(v1[k], wb, ws, poly);
#pragma unroll
        for (int k = 0; k < 4; ++k) r2[k] = kan_elem(v2[k], wb, ws, poly);
#pragma unroll
        for (int k = 0; k < 4; ++k) r3[k] = kan_elem(v3[k], wb, ws, poly);
        o4[i0] = r0;
        o4[i1] = r1;
        o4[i2] = r2;
        o4[i3] = r3;
    } else {
        // generic guard path (not taken for the bench shape)
        int idxs[4] = {i0, i1, i2, i3};
        for (int q = 0; q < 4; ++q) {
            int ii = idxs[q];
            if (ii < n4) {
                fx4 v = x4[ii];
                fx4 r;
#pragma unroll
                for (int k = 0; k < 4; ++k) r[k] = kan_elem(v[k], wb, ws, poly);
                o4[ii] = r;
            }
        }
    }

    // scalar tail (total not divisible by 4)
    int tail_start = n4 * 4;
    for (int k = tail_start + i; k < total; k += stride) {
        out[k] = kan_elem(x[k], wb, ws, poly);
    }
}

extern "C" void kernel_launch(void* const* d_in, const int* in_sizes, int n_in,
                              void* d_out, int out_size, void* d_ws, size_t ws_size,
                              hipStream_t stream) {
    const float* x        = (const float*)d_in[0];
    const float* w_base   = (const float*)d_in[1];
    const float* w_spline = (const float*)d_in[2];
    const float* coeffs   = (const float*)d_in[3];
    float* out = (float*)d_out;

    int total = out_size;           // 8192 * 2048
    int n4 = total / 4;

    int block = 256;
    // each thread covers 4 float4s -> grid for exact cover
    long long threads_needed = (n4 + 3) / 4;
    int grid = (int)((threads_needed + block - 1) / block);
    if (grid < 1) grid = 1;

    kan_edge_kernel<<<grid, block, 0, stream>>>(x, w_base, w_spline, coeffs,
                                                out, n4, total);
}

// Round 7
// 25.334 us; speedup vs baseline: 1.0297x; 1.0297x over previous
//
#include <hip/hip_runtime.h>

// KAN edge function:
//   out = w_base * silu(x) + w_spline * sum_b basis_b(x) * c_b
// Uniform cubic B-spline, GRID_SIZE=8, DEGREE=3 -> 11 bases; knots
// knots[k] = -8.75 + 1.25*k (15 knots, 14 deg-0 intervals). For x in
// interval j with t = (x-knot_j)/h, spline collapses to a per-interval
// cubic a + b t + c t^2 + d t^3 (coeffs built once per block into LDS).
//
// History: R1 26.39us grid-stride. R2 nt REGRESSED (28.9). R4 rcp+clamp
// NEUTRAL (26.38) -> compute off critical path. R5 exact-cover 2xfloat4
// strided-pair WIN (24.8). R6 4xfloat4 REGRESSED (26.1) -> depth 2 is
// the MLP sweet spot. R7: depth 2 with BLOCK-LOCAL pair (i, i+256):
// each block covers one contiguous 8KB window instead of two segments
// 32MB apart -> fewer open DRAM page streams, same perfect coalescing.

constexpr int NUM_BASIS = 11;
constexpr int NUM_INTERVALS = 14;

typedef float fx4 __attribute__((ext_vector_type(4)));

__device__ __forceinline__ float kan_elem(float xv, float wb, float ws,
                                          const float4* __restrict__ poly) {
    // silu: x * sigmoid(x); v_rcp_f32 (~1 ulp) instead of IEEE divide
    float sig = __builtin_amdgcn_rcpf(1.f + __expf(-xv));
    float base = xv * sig;
    // spline: interval index + local param
    float u = (xv + 8.75f) * 0.8f;   // (x - knot0) / h
    float jf = floorf(u);
    float t = u - jf;
    int j = (int)jf;
    // branchless clamp: input is N(0,1) (|x| < ~5.7 << 8.75) -> clamp
    // never changes a reachable value.
    j = min(max(j, 0), NUM_INTERVALS - 1);
    float4 p = poly[j];
    float sp = fmaf(fmaf(fmaf(p.w, t, p.z), t, p.y), t, p.x);
    return fmaf(wb, base, ws * sp);
}

__global__ __launch_bounds__(256) void kan_edge_kernel(
    const float* __restrict__ x,
    const float* __restrict__ w_base_p,
    const float* __restrict__ w_spline_p,
    const float* __restrict__ coeffs,
    float* __restrict__ out,
    int n4, int total)
{
    __shared__ float4 poly[NUM_INTERVALS];

    int tid = threadIdx.x;
    if (tid < NUM_INTERVALS) {
        int j = tid;
        float c0 = (j - 3 >= 0 && j - 3 < NUM_BASIS) ? coeffs[j - 3] : 0.f;
        float c1 = (j - 2 >= 0 && j - 2 < NUM_BASIS) ? coeffs[j - 2] : 0.f;
        float c2 = (j - 1 >= 0 && j - 1 < NUM_BASIS) ? coeffs[j - 1] : 0.f;
        float c3 = (j     < NUM_BASIS)               ? coeffs[j]     : 0.f;
        float a  = (c0 + 4.f * c1 + c2) * (1.f / 6.f);
        float b  = (c2 - c0) * 0.5f;
        float cc = (c0 - 2.f * c1 + c2) * 0.5f;
        float dd = (3.f * (c1 - c2) + (c3 - c0)) * (1.f / 6.f);
        poly[j] = make_float4(a, b, cc, dd);
    }
    __syncthreads();

    const float wb = w_base_p[0];
    const float ws = w_spline_p[0];

    const fx4* __restrict__ x4 = (const fx4*)x;
    fx4* __restrict__ o4 = (fx4*)out;

    // block-local pair: block covers float4s [blk*512, blk*512+512);
    // thread does i0 = base+tid and i1 = i0+256. Both loads coalesced
    // (1 KB/wave/instruction), both within the block's 8 KB window.
    int base = blockIdx.x * (2 * 256);
    int i0 = base + tid;
    int i1 = i0 + 256;

    if (i1 < n4) {
        fx4 va = x4[i0];
        fx4 vb = x4[i1];
        fx4 ra, rb;
#pragma unroll
        for (int k = 0; k < 4; ++k) ra[k] = kan_elem(va[k], wb, ws, poly);
#pragma unroll
        for (int k = 0; k < 4; ++k) rb[k] = kan_elem(vb[k], wb, ws, poly);
        o4[i0] = ra;
        o4[i1] = rb;
    } else {
        // guard path (not taken for the bench shape)
        if (i0 < n4) {
            fx4 v = x4[i0];
            fx4 r;
#pragma unroll
            for (int k = 0; k < 4; ++k) r[k] = kan_elem(v[k], wb, ws, poly);
            o4[i0] = r;
        }
    }

    // scalar tail (total not divisible by 4)
    int gthreads = gridDim.x * blockDim.x;
    int gid = blockIdx.x * blockDim.x + tid;
    int tail_start = n4 * 4;
    for (int k = tail_start + gid; k < total; k += gthreads) {
        out[k] = kan_elem(x[k], wb, ws, poly);
    }
}

extern "C" void kernel_launch(void* const* d_in, const int* in_sizes, int n_in,
                              void* d_out, int out_size, void* d_ws, size_t ws_size,
                              hipStream_t stream) {
    const float* x        = (const float*)d_in[0];
    const float* w_base   = (const float*)d_in[1];
    const float* w_spline = (const float*)d_in[2];
    const float* coeffs   = (const float*)d_in[3];
    float* out = (float*)d_out;

    int total = out_size;           // 8192 * 2048
    int n4 = total / 4;

    int block = 256;
    // each block covers 512 float4s (8 KB)
    long long blocks_needed = (n4 + 511) / 512;
    int grid = (int)blocks_needed;
    if (grid < 1) grid = 1;

    kan_edge_kernel<<<grid, block, 0, stream>>>(x, w_base, w_spline, coeffs,
                                                out, n4, total);
}

// Round 8
// 24.812 us; speedup vs baseline: 1.0513x; 1.0210x over previous
//
#include <hip/hip_runtime.h>

// KAN edge function:
//   out = w_base * silu(x) + w_spline * sum_b basis_b(x) * c_b
// Uniform cubic B-spline, GRID_SIZE=8, DEGREE=3 -> 11 bases; knots
// knots[k] = -8.75 + 1.25*k (15 knots, 14 deg-0 intervals). For x in
// interval j with t = (x-knot_j)/h, spline collapses to a per-interval
// cubic a + b t + c t^2 + d t^3 (coeffs built once per block into LDS).
//
// Ladder: R1 grid-stride 26.39us. R2 nt loads 28.9 (LOSS — normal cache
// path wins). R4 rcp+clamp 26.38 (NULL — compute off critical path).
// R5 exact-cover 2xfloat4 strided pair 24.84 (WIN — best). R6 depth-4
// 26.09 (LOSS). R7 block-local pair 25.33 (LOSS). This is R5 verbatim:
// depth-2 is the MLP optimum; neighbors regress in every direction.
// Floor arithmetic: 134 MB @ 6.29 TB/s copy ceiling = 21.3us; residual
// ~3.5us = dispatch ramp + mixed-stream turnaround (invariant across
// three compute bodies).

constexpr int NUM_BASIS = 11;
constexpr int NUM_INTERVALS = 14;

typedef float fx4 __attribute__((ext_vector_type(4)));

__device__ __forceinline__ float kan_elem(float xv, float wb, float ws,
                                          const float4* __restrict__ poly) {
    // silu: x * sigmoid(x); v_rcp_f32 (~1 ulp) instead of IEEE divide
    float sig = __builtin_amdgcn_rcpf(1.f + __expf(-xv));
    float base = xv * sig;
    // spline: interval index + local param
    float u = (xv + 8.75f) * 0.8f;   // (x - knot0) / h
    float jf = floorf(u);
    float t = u - jf;
    int j = (int)jf;
    // branchless clamp: input is N(0,1) (|x| < ~5.7 << 8.75) -> clamp
    // never changes a reachable value.
    j = min(max(j, 0), NUM_INTERVALS - 1);
    float4 p = poly[j];
    float sp = fmaf(fmaf(fmaf(p.w, t, p.z), t, p.y), t, p.x);
    return fmaf(wb, base, ws * sp);
}

__global__ __launch_bounds__(256) void kan_edge_kernel(
    const float* __restrict__ x,
    const float* __restrict__ w_base_p,
    const float* __restrict__ w_spline_p,
    const float* __restrict__ coeffs,
    float* __restrict__ out,
    int n4, int total)
{
    __shared__ float4 poly[NUM_INTERVALS];

    int tid = threadIdx.x;
    if (tid < NUM_INTERVALS) {
        int j = tid;
        float c0 = (j - 3 >= 0 && j - 3 < NUM_BASIS) ? coeffs[j - 3] : 0.f;
        float c1 = (j - 2 >= 0 && j - 2 < NUM_BASIS) ? coeffs[j - 2] : 0.f;
        float c2 = (j - 1 >= 0 && j - 1 < NUM_BASIS) ? coeffs[j - 1] : 0.f;
        float c3 = (j     < NUM_BASIS)               ? coeffs[j]     : 0.f;
        float a  = (c0 + 4.f * c1 + c2) * (1.f / 6.f);
        float b  = (c2 - c0) * 0.5f;
        float cc = (c0 - 2.f * c1 + c2) * 0.5f;
        float dd = (3.f * (c1 - c2) + (c3 - c0)) * (1.f / 6.f);
        poly[j] = make_float4(a, b, cc, dd);
    }
    __syncthreads();

    const float wb = w_base_p[0];
    const float ws = w_spline_p[0];

    const fx4* __restrict__ x4 = (const fx4*)x;
    fx4* __restrict__ o4 = (fx4*)out;

    // exact cover: each thread handles float4 #i and #(i+stride);
    // stride = total threads, so every load instruction in a wave
    // covers a contiguous 1 KB segment.
    int i = blockIdx.x * blockDim.x + threadIdx.x;
    int stride = gridDim.x * blockDim.x;

    if (i < n4) {
        fx4 va = x4[i];
        int i2 = i + stride;
        bool has2 = i2 < n4;
        fx4 vb = has2 ? x4[i2] : va;
        fx4 ra, rb;
#pragma unroll
        for (int k = 0; k < 4; ++k) ra[k] = kan_elem(va[k], wb, ws, poly);
#pragma unroll
        for (int k = 0; k < 4; ++k) rb[k] = kan_elem(vb[k], wb, ws, poly);
        o4[i] = ra;
        if (has2) o4[i2] = rb;
    }

    // scalar tail (total not divisible by 4)
    int tail_start = n4 * 4;
    for (int k = tail_start + i; k < total; k += stride) {
        out[k] = kan_elem(x[k], wb, ws, poly);
    }
}

extern "C" void kernel_launch(void* const* d_in, const int* in_sizes, int n_in,
                              void* d_out, int out_size, void* d_ws, size_t ws_size,
                              hipStream_t stream) {
    const float* x        = (const float*)d_in[0];
    const float* w_base   = (const float*)d_in[1];
    const float* w_spline = (const float*)d_in[2];
    const float* coeffs   = (const float*)d_in[3];
    float* out = (float*)d_out;

    int total = out_size;           // 8192 * 2048
    int n4 = total / 4;

    int block = 256;
    // each thread covers 2 float4s -> grid for exact cover
    long long threads_needed = (n4 + 1) / 2;
    int grid = (int)((threads_needed + block - 1) / block);
    if (grid < 1) grid = 1;

    kan_edge_kernel<<<grid, block, 0, stream>>>(x, w_base, w_spline, coeffs,
                                                out, n4, total);
}